// Round 9
// baseline (7016.901 us; speedup 1.0000x reference)
//
#include <hip/hip_runtime.h>

#define T_ 1024
#define B_ 32
#define D_ 512
#define FF_ 2048
#define TB_ 32768   // T_*B_
#define TCH_ 256    // T chunk
#define RCH_ 8192   // TCH_*B_ rows per chunk

typedef short bf16x8 __attribute__((ext_vector_type(8)));
typedef float f32x4 __attribute__((ext_vector_type(4)));

static __device__ __forceinline__ unsigned int pack2bf(float a, float b){
  union { __bf16 h[2]; unsigned int u; } z;
  z.h[0] = (__bf16)a; z.h[1] = (__bf16)b; return z.u;
}
static __device__ __forceinline__ float bflo(unsigned int u){ return __uint_as_float(u<<16); }
static __device__ __forceinline__ float bfhi(unsigned int u){ return __uint_as_float(u & 0xffff0000u); }
static __device__ __forceinline__ float sigm(float x){ return 1.f/(1.f+__expf(-x)); }
static __device__ __forceinline__ float tanh_(float x){ return 1.f - 2.f/(1.f+__expf(2.f*x)); }

// first[] may be uint8 (numpy bool) or int32; detected at runtime.
static __device__ __forceinline__ bool firstval(const void* p, int mode, int idx){
  return mode ? (((const int*)p)[idx] != 0) : (((const unsigned char*)p)[idx] != 0);
}

// ---------------------------------------------------------------- detect bool dtype
__global__ void detect_first_kernel(const unsigned char* __restrict__ p, unsigned int* __restrict__ mode){
  __shared__ int found;
  if (threadIdx.x == 0) found = 0;
  __syncthreads();
  int f = 0;
  for (int i = threadIdx.x; i < TB_; i += 256) if ((i & 3) != 0 && p[i] != 0) f = 1;
  if (f) atomicAdd(&found, 1);
  __syncthreads();
  if (threadIdx.x == 0) *mode = (found == 0) ? 1u : 0u;   // 1 => int32, 0 => uint8
}

// ---------------------------------------------------------------- weight conversion
__global__ void convert_w_kernel(const float* __restrict__ Wih, const float* __restrict__ Whh,
                                 const float* __restrict__ m0w, const float* __restrict__ m1w,
                                 const float* __restrict__ aw0, const float* __restrict__ aw1,
                                 __bf16* __restrict__ Wihb, __bf16* __restrict__ Whhb,
                                 __bf16* __restrict__ m0b,  __bf16* __restrict__ m1b,
                                 __bf16* __restrict__ awT0, __bf16* __restrict__ awT1){
  int bid = blockIdx.x;
  if (bid < 4096) {
    int ai = bid >> 10;
    size_t off = (size_t)(bid & 1023) * 1024 + threadIdx.x * 4;
    const float* src = (ai==0)?Wih:(ai==1)?Whh:(ai==2)?m0w:m1w;
    __bf16* dst = (ai==0)?Wihb:(ai==1)?Whhb:(ai==2)?m0b:m1b;
    float4 v = *(const float4*)(src + off);
    union { __bf16 h[4]; uint2 u; } z;
    z.h[0]=(__bf16)v.x; z.h[1]=(__bf16)v.y; z.h[2]=(__bf16)v.z; z.h[3]=(__bf16)v.w;
    *(uint2*)(void*)(dst + off) = z.u;
  } else {
    int e = (bid - 4096) * 256 + threadIdx.x;      // 0..65535
    if (e < 32768) { int k = e >> 6, j = e & 63;  awT0[e] = (__bf16)aw0[j*512 + k]; }
    else { int e2 = e - 32768; int j = e2 >> 9, d = e2 & 511; awT1[e2] = (__bf16)aw1[d*64 + j]; }
  }
}

// ---------------------------------------------------------------- layernorm -> bf16 (chunk of 8192 rows)
__global__ __launch_bounds__(256) void ln_kernel(const float* __restrict__ x,
                                                 const float* __restrict__ g, const float* __restrict__ b,
                                                 __bf16* __restrict__ xn){
  const int w = threadIdx.x >> 6, l = threadIdx.x & 63;
  const int row = blockIdx.x * 4 + w;
  const float* xr = x + (size_t)row * D_;
  const int e0 = l * 4, e1 = 256 + l * 4;
  float4 v0 = *(const float4*)(xr + e0);
  float4 v1 = *(const float4*)(xr + e1);
  float s  = v0.x+v0.y+v0.z+v0.w + v1.x+v1.y+v1.z+v1.w;
  float s2 = v0.x*v0.x+v0.y*v0.y+v0.z*v0.z+v0.w*v0.w + v1.x*v1.x+v1.y*v1.y+v1.z*v1.z+v1.w*v1.w;
  #pragma unroll
  for (int off = 1; off < 64; off <<= 1) { s += __shfl_xor(s, off); s2 += __shfl_xor(s2, off); }
  float mu = s * (1.f/512.f);
  float var = s2 * (1.f/512.f) - mu*mu;
  float rstd = rsqrtf(var + 1e-5f);
  float4 g0 = *(const float4*)(g + e0), g1 = *(const float4*)(g + e1);
  float4 b0 = *(const float4*)(b + e0), b1 = *(const float4*)(b + e1);
  union { __bf16 h[4]; uint2 u; } o0, o1;
  o0.h[0]=(__bf16)((v0.x-mu)*rstd*g0.x+b0.x); o0.h[1]=(__bf16)((v0.y-mu)*rstd*g0.y+b0.y);
  o0.h[2]=(__bf16)((v0.z-mu)*rstd*g0.z+b0.z); o0.h[3]=(__bf16)((v0.w-mu)*rstd*g0.w+b0.w);
  o1.h[0]=(__bf16)((v1.x-mu)*rstd*g1.x+b1.x); o1.h[1]=(__bf16)((v1.y-mu)*rstd*g1.y+b1.y);
  o1.h[2]=(__bf16)((v1.z-mu)*rstd*g1.z+b1.z); o1.h[3]=(__bf16)((v1.w-mu)*rstd*g1.w+b1.w);
  *(uint2*)(void*)(xn + (size_t)row * D_ + e0) = o0.u;
  *(uint2*)(void*)(xn + (size_t)row * D_ + e1) = o1.u;
}

// ---------------------------------------------------------------- bf16 "BT" GEMM  C[M,N] = A[M,K] @ W[N,K]^T + bias
template<int RELU, int BF16OUT, int TWOBIAS>
__global__ __launch_bounds__(256) void gemm_bt(const __bf16* __restrict__ A, const __bf16* __restrict__ W,
                                               const float* __restrict__ bias0, const float* __restrict__ bias1,
                                               float* __restrict__ Cf, __bf16* __restrict__ Cb,
                                               int M, int N, int K){
  __shared__ __bf16 As[128*64];
  __shared__ __bf16 Bs[128*64];
  const int tid = threadIdx.x, w = tid >> 6, l = tid & 63;
  const int bm = blockIdx.x, bn = blockIdx.y;
  const int wm = (w >> 1) * 64, wn = (w & 1) * 64;
  const int nk = K >> 6;

  uint4 ra[4], rb[4];
  #pragma unroll
  for (int i = 0; i < 4; ++i) {
    int s = tid + (i << 8); int row = s >> 3; int ks = s & 7;
    ra[i] = *(const uint4*)(void*)(A + (size_t)(bm*128 + row) * K + ks*8);
    rb[i] = *(const uint4*)(void*)(W + (size_t)(bn*128 + row) * K + ks*8);
  }
  f32x4 acc[4][4];
  #pragma unroll
  for (int mt = 0; mt < 4; ++mt)
    #pragma unroll
    for (int nt = 0; nt < 4; ++nt) acc[mt][nt] = (f32x4){0.f,0.f,0.f,0.f};

  for (int kt = 0; kt < nk; ++kt) {
    __syncthreads();
    #pragma unroll
    for (int i = 0; i < 4; ++i) {
      int s = tid + (i << 8); int row = s >> 3; int ks = s & 7;
      int wi = row * 64 + ((ks * 8) ^ ((row & 7) << 3));   // XOR swizzle (elements)
      *(uint4*)(void*)(As + wi) = ra[i];
      *(uint4*)(void*)(Bs + wi) = rb[i];
    }
    __syncthreads();
    if (kt + 1 < nk) {
      #pragma unroll
      for (int i = 0; i < 4; ++i) {
        int s = tid + (i << 8); int row = s >> 3; int ks = s & 7;
        ra[i] = *(const uint4*)(void*)(A + (size_t)(bm*128 + row) * K + (kt+1)*64 + ks*8);
        rb[i] = *(const uint4*)(void*)(W + (size_t)(bn*128 + row) * K + (kt+1)*64 + ks*8);
      }
    }
    #pragma unroll
    for (int kk = 0; kk < 2; ++kk) {
      bf16x8 af[4], bfv[4];
      const int ke = kk * 32 + ((l >> 4) << 3);
      #pragma unroll
      for (int mt = 0; mt < 4; ++mt) {
        int row = wm + mt*16 + (l & 15);
        af[mt] = *(const bf16x8*)(void*)(As + row*64 + (ke ^ ((row & 7) << 3)));
      }
      #pragma unroll
      for (int nt = 0; nt < 4; ++nt) {
        int row = wn + nt*16 + (l & 15);
        bfv[nt] = *(const bf16x8*)(void*)(Bs + row*64 + (ke ^ ((row & 7) << 3)));
      }
      #pragma unroll
      for (int mt = 0; mt < 4; ++mt)
        #pragma unroll
        for (int nt = 0; nt < 4; ++nt)
          acc[mt][nt] = __builtin_amdgcn_mfma_f32_16x16x32_bf16(af[mt], bfv[nt], acc[mt][nt], 0, 0, 0);
    }
  }
  // epilogue: D row = (l>>4)*4+j, col = l&15 (m89-verified layout)
  #pragma unroll
  for (int nt = 0; nt < 4; ++nt) {
    int c = bn*128 + wn + nt*16 + (l & 15);
    float bv = bias0[c];
    if (TWOBIAS) bv += bias1[c];
    #pragma unroll
    for (int mt = 0; mt < 4; ++mt) {
      #pragma unroll
      for (int j = 0; j < 4; ++j) {
        int r = bm*128 + wm + mt*16 + ((l >> 4) << 2) + j;
        float v = acc[mt][nt][j] + bv;
        if (RELU) v = fmaxf(v, 0.f);
        if (BF16OUT) Cb[(size_t)r * N + c] = (__bf16)v;
        else         Cf[(size_t)r * N + c] = v;
      }
    }
  }
}

// ---------------------------------------------------------------- LSTM scan chunk
// 16 persistent WGs. H exchange via self-validating 8B packets
//   (hi32 = step tag, lo32 = 2 x bf16 payload), relaxed agent-scope atomics, 1 hop/step.
// MAILBOX FANOUT: each producer thread stores its packet into 16 per-consumer mailboxes
//   HP[2][16][8192]; consumer s polls ONLY HP[parity][s][*] -> each cache line is read by
//   exactly one WG (kills LLC line contention from 16 WGs polling shared lines).
// Double-buffered by parity; producer overwrites parity p for t+2 only after consuming all
// tags t+1, which certifies every WG finished its step-(t-1) reads of p (delay-1 invariant,
// single writer per location).
__global__ __launch_bounds__(512) void lstm_scan(
    const __bf16* __restrict__ Whh,      // [2048][512] bf16
    const __bf16* __restrict__ preC,     // [RCH_][2048] bf16 (chunk-local rows)
    const float*  __restrict__ x,        // residual (global rows)
    const void*   __restrict__ firstp,
    const float*  __restrict__ h0,
    const float*  __restrict__ c0,
    float*        __restrict__ cstate,   // [B_*D_] f32 (pre-multiplied by keep)
    __bf16*       __restrict__ ymidbC,   // [RCH_][512] bf16 (chunk-local rows)
    unsigned long long* __restrict__ HP, // [2][16][8192] packet mailboxes (2 MB)
    const unsigned int* __restrict__ modep,
    float* __restrict__ hout, float* __restrict__ cout,
    int tBase){
  const int s = blockIdx.x, tid = threadIdx.x, w = tid >> 6, l = tid & 63;
  const int d0 = s * 32;
  __shared__ __bf16 Hl[32 * 512];      // staged H, stride 512 + XOR swizzle (2-way max)
  __shared__ float  gl[32 * 132];      // gate exchange, stride 132 (2-way max)
  const int mode = (int)*modep;

  // Whh B-fragments resident in VGPRs: wave w owns gate rows rl = w*16 + (l&15)
  bf16x8 wf[16];
  {
    int rl = w*16 + (l & 15);
    int gr = (rl >> 5) * 512 + d0 + (rl & 31);     // PyTorch gate order i,f,g,o
    const __bf16* base = Whh + (size_t)gr * 512 + ((l >> 4) << 3);
    #pragma unroll
    for (int kt = 0; kt < 16; ++kt) wf[kt] = *(const bf16x8*)(void*)(base + kt*32);
  }
  const int b = tid >> 4, dl2 = (tid & 15) * 2;    // producer role: (batch, dim pair)
  const int dg = d0 + dl2;
  const int opid = b * 256 + s * 16 + (tid & 15);  // own packet id (within a mailbox)

  float cr[2];
  if (tBase == 0) {
    float k0 = firstval(firstp, mode, b) ? 0.f : 1.f;
    float2 c2 = *(const float2*)(c0 + (size_t)b*512 + dg);
    cr[0] = c2.x * k0; cr[1] = c2.y * k0;
    float2 h = *(const float2*)(h0 + (size_t)b*512 + dg);
    unsigned long long pkt = (1ULL << 32) | (unsigned long long)pack2bf(h.x*k0, h.y*k0);
    #pragma unroll
    for (int cons = 0; cons < 16; ++cons)
      __hip_atomic_store(HP + cons*8192 + opid, pkt, __ATOMIC_RELAXED, __HIP_MEMORY_SCOPE_AGENT);
  } else {
    float2 c2 = *(const float2*)(cstate + (size_t)b*512 + dg);
    cr[0] = c2.x; cr[1] = c2.y;
  }

  for (int tl = 0; tl < TCH_; ++tl) {
    const int t = tBase + tl;
    const int rowg = t * 32 + b, rowl = tl * 32 + b;
    // prefetch (overlaps the poll below)
    unsigned int pg[4];
    #pragma unroll
    for (int gi = 0; gi < 4; ++gi)
      pg[gi] = *(const unsigned int*)(void*)(preC + (size_t)rowl * 2048 + gi*512 + dg);
    float2 xv = *(const float2*)(x + (size_t)rowg * 512 + dg);
    const bool f_t1 = (t < T_-1) ? firstval(firstp, mode, rowg + 32) : false;

    // ---- poll OWN mailbox: coalesced loads (thread tid owns pids {tid + j*512})
    const unsigned want = (unsigned)(t + 1);
    const unsigned long long* Pb = HP + (((size_t)(t & 1)) << 17) + (size_t)s*8192;
    unsigned long long pk[16];
    #pragma unroll
    for (int j = 0; j < 16; ++j)
      pk[j] = __hip_atomic_load(Pb + tid + (j << 9), __ATOMIC_RELAXED, __HIP_MEMORY_SCOPE_AGENT);
    while (true) {
      unsigned stale = 0;
      #pragma unroll
      for (int j = 0; j < 16; ++j)
        if ((unsigned)(pk[j] >> 32) != want) stale |= (1u << j);
      if (!stale) break;
      __builtin_amdgcn_s_sleep(1);
      #pragma unroll
      for (int j = 0; j < 16; ++j)
        if (stale & (1u << j))
          pk[j] = __hip_atomic_load(Pb + tid + (j << 9), __ATOMIC_RELAXED, __HIP_MEMORY_SCOPE_AGENT);
    }
    // payloads -> LDS: pid = pb*256 + ps*16 + pi -> row pb, elems ps*32 + pi*2 (swizzled)
    #pragma unroll
    for (int j = 0; j < 16; ++j) {
      int pid = tid + (j << 9);
      int pb = pid >> 8, ps = (pid >> 4) & 15, pi = pid & 15;
      int q = ps*32 + pi*2;
      *(unsigned int*)(void*)(Hl + pb*512 + (q ^ ((pb & 7) << 3))) = (unsigned)pk[j];
    }
    __syncthreads();

    // ---- gates[b, rl] = H @ Whh_slice^T  (2 interleaved chains per acc, 8-deep)
    f32x4 a0a = (f32x4){0.f,0.f,0.f,0.f}, a0b = (f32x4){0.f,0.f,0.f,0.f};
    f32x4 a1a = (f32x4){0.f,0.f,0.f,0.f}, a1b = (f32x4){0.f,0.f,0.f,0.f};
    #pragma unroll
    for (int kt = 0; kt < 16; kt += 2) {
      int ke0 = kt*32 + ((l >> 4) << 3), ke1 = (kt+1)*32 + ((l >> 4) << 3);
      int r0 = (l & 15), r1 = 16 + (l & 15);
      bf16x8 h00 = *(const bf16x8*)(void*)(Hl + r0*512 + (ke0 ^ ((r0 & 7) << 3)));
      bf16x8 h01 = *(const bf16x8*)(void*)(Hl + r0*512 + (ke1 ^ ((r0 & 7) << 3)));
      bf16x8 h10 = *(const bf16x8*)(void*)(Hl + r1*512 + (ke0 ^ ((r1 & 7) << 3)));
      bf16x8 h11 = *(const bf16x8*)(void*)(Hl + r1*512 + (ke1 ^ ((r1 & 7) << 3)));
      a0a = __builtin_amdgcn_mfma_f32_16x16x32_bf16(h00, wf[kt],   a0a, 0, 0, 0);
      a0b = __builtin_amdgcn_mfma_f32_16x16x32_bf16(h01, wf[kt+1], a0b, 0, 0, 0);
      a1a = __builtin_amdgcn_mfma_f32_16x16x32_bf16(h10, wf[kt],   a1a, 0, 0, 0);
      a1b = __builtin_amdgcn_mfma_f32_16x16x32_bf16(h11, wf[kt+1], a1b, 0, 0, 0);
    }
    f32x4 acc0 = a0a + a0b, acc1 = a1a + a1b;
    // ---- gate exchange through LDS (stride 132: 2-way max both sides)
    {
      int col = w*16 + (l & 15);
      #pragma unroll
      for (int j = 0; j < 4; ++j) {
        gl[(((l >> 4) << 2) + j) * 132 + col]        = acc0[j];
        gl[((16 + ((l >> 4) << 2) + j)) * 132 + col] = acc1[j];
      }
    }
    __syncthreads();

    // ---- cell update for (b, dg), (b, dg+1); cr pre-multiplied by keep(first[t])
    float2 gv[4];
    #pragma unroll
    for (int gi = 0; gi < 4; ++gi) gv[gi] = *(const float2*)(gl + b*132 + gi*32 + dl2);
    const float keep1 = f_t1 ? 0.f : 1.f;
    float hh[2], cc[2];
    #pragma unroll
    for (int p = 0; p < 2; ++p) {
      float gi_ = (p ? gv[0].y : gv[0].x) + (p ? bfhi(pg[0]) : bflo(pg[0]));
      float gf_ = (p ? gv[1].y : gv[1].x) + (p ? bfhi(pg[1]) : bflo(pg[1]));
      float gg_ = (p ? gv[2].y : gv[2].x) + (p ? bfhi(pg[2]) : bflo(pg[2]));
      float go_ = (p ? gv[3].y : gv[3].x) + (p ? bfhi(pg[3]) : bflo(pg[3]));
      float cn = sigm(gf_) * cr[p] + sigm(gi_) * tanh_(gg_);
      float h  = sigm(go_) * tanh_(cn);
      cc[p] = cn; hh[p] = h;
    }
    cr[0] = cc[0] * keep1; cr[1] = cc[1] * keep1;
    float2 yv = { hh[0] + xv.x, hh[1] + xv.y };
    if (t < T_-1) {
      // publish own packet (tag t+2) into all 16 mailboxes -- this IS the release
      unsigned long long pkt = (((unsigned long long)(unsigned)(t + 2)) << 32)
                             | (unsigned long long)pack2bf(hh[0]*keep1, hh[1]*keep1);
      unsigned long long* Wb = HP + (((size_t)((t+1) & 1)) << 17);
      #pragma unroll
      for (int cons = 0; cons < 16; ++cons)
        __hip_atomic_store(Wb + cons*8192 + opid, pkt, __ATOMIC_RELAXED, __HIP_MEMORY_SCOPE_AGENT);
      if (tl == TCH_-1) *(float2*)(cstate + (size_t)b*512 + dg) = make_float2(cr[0], cr[1]);
    } else {
      *(float2*)(hout + (size_t)b*512 + dg) = make_float2(hh[0], hh[1]);
      *(float2*)(cout + (size_t)b*512 + dg) = make_float2(cc[0], cc[1]);
    }
    // no end-of-iter barrier: next iteration's post-stage __syncthreads orders LDS reuse.
    *(unsigned int*)(void*)(ymidbC + (size_t)rowl * 512 + dg) = pack2bf(yv.x, yv.y);
  }
}

// ---------------------------------------------------------------- fused adapter + final residual (in-place on y2)
__global__ __launch_bounds__(256) void adapter_out_kernel(
    float* __restrict__ y2,              // [RCH_][512] in/out (lives in d_out)
    const __bf16* __restrict__ ymidb,    // [RCH_][512]
    const __bf16* __restrict__ awT0,     // [512][64] = aw0^T
    const __bf16* __restrict__ awT1,     // [64][512] = aw1^T
    const float* __restrict__ ab0, const float* __restrict__ ab1){
  __shared__ float zl[16 * 64];
  const int w = threadIdx.x >> 6, l = threadIdx.x & 63;
  const int r0 = blockIdx.x * 16;
  const float bz = ab0[l];
  #pragma unroll
  for (int rr = 0; rr < 4; ++rr) {
    int rowl = w*4 + rr;
    const float* yr = y2 + (size_t)(r0 + rowl) * 512;
    float acc = bz;
    #pragma unroll 4
    for (int k = 0; k < 512; ++k) acc += yr[k] * (float)awT0[k*64 + l];
    zl[rowl*64 + l] = fmaxf(acc, 0.f);
  }
  __syncthreads();
  #pragma unroll
  for (int rr = 0; rr < 4; ++rr) {
    int rowl = w*4 + rr; int row = r0 + rowl;
    const float* yr = y2  + (size_t)row * 512;
    const __bf16* mr = ymidb + (size_t)row * 512;
    #pragma unroll
    for (int dd = 0; dd < 8; ++dd) {
      int d = dd*64 + l;
      float acc = ab1[d] + yr[d] + (float)mr[d];
      #pragma unroll 4
      for (int j = 0; j < 64; ++j) acc += zl[rowl*64 + j] * (float)awT1[j*512 + d];
      y2[(size_t)row * 512 + d] = acc;
    }
  }
}

// ---------------------------------------------------------------- launch
extern "C" void kernel_launch(void* const* d_in, const int* in_sizes, int n_in,
                              void* d_out, int out_size, void* d_ws, size_t ws_size,
                              hipStream_t stream){
  (void)in_sizes; (void)n_in; (void)out_size; (void)ws_size;
  const float* x    = (const float*)d_in[0];
  const void*  first=               d_in[1];
  const float* h0   = (const float*)d_in[2];
  const float* c0   = (const float*)d_in[3];
  const float* ln_g = (const float*)d_in[4];
  const float* ln_b = (const float*)d_in[5];
  const float* Wih  = (const float*)d_in[6];
  const float* Whh  = (const float*)d_in[7];
  const float* bih  = (const float*)d_in[8];
  const float* bhh  = (const float*)d_in[9];
  const float* m0w  = (const float*)d_in[10];
  const float* m0b  = (const float*)d_in[11];
  const float* m1w  = (const float*)d_in[12];
  const float* m1b  = (const float*)d_in[13];
  const float* aw0  = (const float*)d_in[14];
  const float* ab0  = (const float*)d_in[15];
  const float* aw1  = (const float*)d_in[16];
  const float* ab1  = (const float*)d_in[17];

  // workspace layout — total ~61.1 MB
  char* ws = (char*)d_ws;
  __bf16* buf0  = (__bf16*)(ws + 0LL);            // 32 MB: preC, later a1C (disjoint lifetimes per chunk)
  __bf16* xnbfC = (__bf16*)(ws + 33554432LL);     // 8 MB
  __bf16* ymidbC= (__bf16*)(ws + 41943040LL);     // 8 MB
  __bf16* wihb  = (__bf16*)(ws + 50331648LL);     // 2 MB
  __bf16* whhb  = (__bf16*)(ws + 52428800LL);     // 2 MB
  __bf16* m0bf  = (__bf16*)(ws + 54525952LL);     // 2 MB
  __bf16* m1bf  = (__bf16*)(ws + 56623104LL);     // 2 MB
  __bf16* awT0  = (__bf16*)(ws + 58720256LL);     // 64 KB
  __bf16* awT1  = (__bf16*)(ws + 58785792LL);     // 64 KB
  unsigned long long* HP = (unsigned long long*)(ws + 58851328LL);  // 2 MB mailbox packets
  float*  cstate= (float*) (ws + 60948480LL);     // 64 KB
  unsigned int* mode = (unsigned int*)(ws + 61014016LL);
  __bf16* preC = buf0;
  __bf16* a1C  = buf0;

  float* out  = (float*)d_out;
  float* hout = out + (size_t)TB_ * D_;
  float* cout = hout + B_ * D_;

  // zero packet mailboxes: kills cross-replay stale-tag aliasing
  hipMemsetAsync(HP, 0, 2097152, stream);
  detect_first_kernel<<<1, 256, 0, stream>>>((const unsigned char*)first, mode);
  convert_w_kernel<<<4352, 256, 0, stream>>>(Wih, Whh, m0w, m1w, aw0, aw1,
                                             wihb, whhb, m0bf, m1bf, awT0, awT1);
  for (int c = 0; c < 4; ++c) {
    const size_t ro = (size_t)c * RCH_;
    ln_kernel<<<RCH_/4, 256, 0, stream>>>(x + ro * D_, ln_g, ln_b, xnbfC);
    gemm_bt<0,1,1><<<dim3(RCH_/128, FF_/128), 256, 0, stream>>>(xnbfC, wihb, bih, bhh,
                                                                nullptr, preC, RCH_, 2048, 512);
    lstm_scan<<<16, 512, 0, stream>>>(whhb, preC, x, first, h0, c0, cstate, ymidbC,
                                      HP, mode, hout, cout, c * TCH_);
    gemm_bt<1,1,0><<<dim3(RCH_/128, FF_/128), 256, 0, stream>>>(ymidbC, m0bf, m0b, nullptr,
                                                                nullptr, a1C, RCH_, FF_, 512);
    gemm_bt<0,0,0><<<dim3(RCH_/128, D_/128), 256, 0, stream>>>(a1C, m1bf, m1b, nullptr,
                                                               out + ro * D_, nullptr, RCH_, D_, FF_);
    adapter_out_kernel<<<RCH_/16, 256, 0, stream>>>(out + ro * D_, ymidbC, awT0, awT1, ab0, ab1);
  }
}

// Round 10
// 6893.862 us; speedup vs baseline: 1.0178x; 1.0178x over previous
//
#include <hip/hip_runtime.h>

#define T_ 1024
#define B_ 32
#define D_ 512
#define FF_ 2048
#define TB_ 32768   // T_*B_
#define TCH_ 256    // T chunk
#define RCH_ 8192   // TCH_*B_ rows per chunk

typedef short bf16x8 __attribute__((ext_vector_type(8)));
typedef float f32x4 __attribute__((ext_vector_type(4)));

union SharedU {
  struct { __bf16 Hl[32*512]; float gl[32*132]; } s;            // scan: 49664 B
  struct { __bf16 As[128*64]; __bf16 Bs[128*64]; float stat[256]; } g; // gemm: 33792 B
  float zl[128*64];                                              // adapter: 32768 B
};

static __device__ __forceinline__ unsigned int pack2bf(float a, float b){
  union { __bf16 h[2]; unsigned int u; } z;
  z.h[0] = (__bf16)a; z.h[1] = (__bf16)b; return z.u;
}
static __device__ __forceinline__ float bflo(unsigned int u){ return __uint_as_float(u<<16); }
static __device__ __forceinline__ float bfhi(unsigned int u){ return __uint_as_float(u & 0xffff0000u); }
static __device__ __forceinline__ float sigm(float x){ return 1.f/(1.f+__expf(-x)); }
static __device__ __forceinline__ float tanh_(float x){ return 1.f - 2.f/(1.f+__expf(2.f*x)); }

static __device__ __forceinline__ bool firstval(const void* p, int mode, int idx){
  return mode ? (((const int*)p)[idx] != 0) : (((const unsigned char*)p)[idx] != 0);
}

// ---------------------------------------------------------------- detect bool dtype
__global__ void detect_first_kernel(const unsigned char* __restrict__ p, unsigned int* __restrict__ mode){
  __shared__ int found;
  if (threadIdx.x == 0) found = 0;
  __syncthreads();
  int f = 0;
  for (int i = threadIdx.x; i < TB_; i += 256) if ((i & 3) != 0 && p[i] != 0) f = 1;
  if (f) atomicAdd(&found, 1);
  __syncthreads();
  if (threadIdx.x == 0) *mode = (found == 0) ? 1u : 0u;
}

// ---------------------------------------------------------------- weight conversion
__global__ void convert_w_kernel(const float* __restrict__ Wih, const float* __restrict__ Whh,
                                 const float* __restrict__ m0w, const float* __restrict__ m1w,
                                 const float* __restrict__ aw0, const float* __restrict__ aw1,
                                 __bf16* __restrict__ Wihb, __bf16* __restrict__ Whhb,
                                 __bf16* __restrict__ m0b,  __bf16* __restrict__ m1b,
                                 __bf16* __restrict__ awT0, __bf16* __restrict__ awT1){
  int bid = blockIdx.x;
  if (bid < 4096) {
    int ai = bid >> 10;
    size_t off = (size_t)(bid & 1023) * 1024 + threadIdx.x * 4;
    const float* src = (ai==0)?Wih:(ai==1)?Whh:(ai==2)?m0w:m1w;
    __bf16* dst = (ai==0)?Wihb:(ai==1)?Whhb:(ai==2)?m0b:m1b;
    float4 v = *(const float4*)(src + off);
    union { __bf16 h[4]; uint2 u; } z;
    z.h[0]=(__bf16)v.x; z.h[1]=(__bf16)v.y; z.h[2]=(__bf16)v.z; z.h[3]=(__bf16)v.w;
    *(uint2*)(void*)(dst + off) = z.u;
  } else {
    int e = (bid - 4096) * 256 + threadIdx.x;
    if (e < 32768) { int k = e >> 6, j = e & 63;  awT0[e] = (__bf16)aw0[j*512 + k]; }
    else { int e2 = e - 32768; int j = e2 >> 9, d = e2 & 511; awT1[e2] = (__bf16)aw1[d*64 + j]; }
  }
}

// ---------------------------------------------------------------- 512-thread 128x128 tile GEMM
// AMODE: 0 = bf16 A normal loads; 1 = bf16 A via 8B agent-atomic (sc0) loads (same-WG RAW);
//        2 = A from f32 x with inline LayerNorm (stats in stat[], params lng/lnb)
template<int RELU,int BF16OUT,int TWOBIAS,int AMODE>
static __device__ void tile_gemm(SharedU& sh,
    const __bf16* A, const float* Ax, const float* lng, const float* lnb,
    const __bf16* W, const float* bias0, const float* bias1,
    float* Cf, __bf16* Cb, int aRow0, int cRow0, int bn, int N, int K){
  __bf16* As = sh.g.As; __bf16* Bs = sh.g.Bs; const float* stat = sh.g.stat;
  const int tid = threadIdx.x, w = tid >> 6, l = tid & 63;
  const int wm = (w >> 2) * 64, wn = (w & 3) * 32;
  const int nk = K >> 6;
  uint4 ra[2], rb[2];
  float4 rx[2][2];
  #pragma unroll
  for (int i = 0; i < 2; ++i) {
    int s = tid + (i << 9); int row = s >> 3; int ks = s & 7;
    if (AMODE == 2) {
      const float* px = Ax + (size_t)(aRow0 + row) * 512 + ks*8;
      rx[i][0] = *(const float4*)px; rx[i][1] = *(const float4*)(px + 4);
    } else if (AMODE == 1) {
      const unsigned long long* pa = (const unsigned long long*)(void*)(A + (size_t)(aRow0 + row) * K + ks*8);
      union { unsigned long long q[2]; uint4 u; } z;
      z.q[0] = __hip_atomic_load(pa,   __ATOMIC_RELAXED, __HIP_MEMORY_SCOPE_AGENT);
      z.q[1] = __hip_atomic_load(pa+1, __ATOMIC_RELAXED, __HIP_MEMORY_SCOPE_AGENT);
      ra[i] = z.u;
    } else {
      ra[i] = *(const uint4*)(void*)(A + (size_t)(aRow0 + row) * K + ks*8);
    }
    rb[i] = *(const uint4*)(void*)(W + (size_t)(bn*128 + row) * K + ks*8);
  }
  f32x4 acc[4][2];
  #pragma unroll
  for (int mt = 0; mt < 4; ++mt)
    #pragma unroll
    for (int nt = 0; nt < 2; ++nt) acc[mt][nt] = (f32x4){0.f,0.f,0.f,0.f};

  for (int kt = 0; kt < nk; ++kt) {
    __syncthreads();
    #pragma unroll
    for (int i = 0; i < 2; ++i) {
      int s = tid + (i << 9); int row = s >> 3; int ks = s & 7;
      int wi = row * 64 + ((ks * 8) ^ ((row & 7) << 3));
      if (AMODE == 2) {
        float mu = stat[row], rs = stat[128 + row];
        int col = kt*64 + ks*8;
        float4 g0 = *(const float4*)(lng + col), g1 = *(const float4*)(lng + col + 4);
        float4 b0 = *(const float4*)(lnb + col), b1 = *(const float4*)(lnb + col + 4);
        union { __bf16 h[8]; uint4 u; } z;
        z.h[0]=(__bf16)((rx[i][0].x-mu)*rs*g0.x+b0.x); z.h[1]=(__bf16)((rx[i][0].y-mu)*rs*g0.y+b0.y);
        z.h[2]=(__bf16)((rx[i][0].z-mu)*rs*g0.z+b0.z); z.h[3]=(__bf16)((rx[i][0].w-mu)*rs*g0.w+b0.w);
        z.h[4]=(__bf16)((rx[i][1].x-mu)*rs*g1.x+b1.x); z.h[5]=(__bf16)((rx[i][1].y-mu)*rs*g1.y+b1.y);
        z.h[6]=(__bf16)((rx[i][1].z-mu)*rs*g1.z+b1.z); z.h[7]=(__bf16)((rx[i][1].w-mu)*rs*g1.w+b1.w);
        *(uint4*)(void*)(As + wi) = z.u;
      } else {
        *(uint4*)(void*)(As + wi) = ra[i];
      }
      *(uint4*)(void*)(Bs + wi) = rb[i];
    }
    __syncthreads();
    if (kt + 1 < nk) {
      #pragma unroll
      for (int i = 0; i < 2; ++i) {
        int s = tid + (i << 9); int row = s >> 3; int ks = s & 7;
        if (AMODE == 2) {
          const float* px = Ax + (size_t)(aRow0 + row) * 512 + (kt+1)*64 + ks*8;
          rx[i][0] = *(const float4*)px; rx[i][1] = *(const float4*)(px + 4);
        } else if (AMODE == 1) {
          const unsigned long long* pa = (const unsigned long long*)(void*)(A + (size_t)(aRow0 + row) * K + (kt+1)*64 + ks*8);
          union { unsigned long long q[2]; uint4 u; } z;
          z.q[0] = __hip_atomic_load(pa,   __ATOMIC_RELAXED, __HIP_MEMORY_SCOPE_AGENT);
          z.q[1] = __hip_atomic_load(pa+1, __ATOMIC_RELAXED, __HIP_MEMORY_SCOPE_AGENT);
          ra[i] = z.u;
        } else {
          ra[i] = *(const uint4*)(void*)(A + (size_t)(aRow0 + row) * K + (kt+1)*64 + ks*8);
        }
        rb[i] = *(const uint4*)(void*)(W + (size_t)(bn*128 + row) * K + (kt+1)*64 + ks*8);
      }
    }
    #pragma unroll
    for (int kk = 0; kk < 2; ++kk) {
      bf16x8 af[4], bfv[2];
      const int ke = kk * 32 + ((l >> 4) << 3);
      #pragma unroll
      for (int mt = 0; mt < 4; ++mt) {
        int row = wm + mt*16 + (l & 15);
        af[mt] = *(const bf16x8*)(void*)(As + row*64 + (ke ^ ((row & 7) << 3)));
      }
      #pragma unroll
      for (int nt = 0; nt < 2; ++nt) {
        int row = wn + nt*16 + (l & 15);
        bfv[nt] = *(const bf16x8*)(void*)(Bs + row*64 + (ke ^ ((row & 7) << 3)));
      }
      #pragma unroll
      for (int mt = 0; mt < 4; ++mt)
        #pragma unroll
        for (int nt = 0; nt < 2; ++nt)
          acc[mt][nt] = __builtin_amdgcn_mfma_f32_16x16x32_bf16(af[mt], bfv[nt], acc[mt][nt], 0, 0, 0);
    }
  }
  #pragma unroll
  for (int nt = 0; nt < 2; ++nt) {
    int c = bn*128 + wn + nt*16 + (l & 15);
    float bv = bias0[c];
    if (TWOBIAS) bv += bias1[c];
    #pragma unroll
    for (int mt = 0; mt < 4; ++mt) {
      #pragma unroll
      for (int j = 0; j < 4; ++j) {
        int r = cRow0 + wm + mt*16 + ((l >> 4) << 2) + j;
        float v = acc[mt][nt][j] + bv;
        if (RELU) v = fmaxf(v, 0.f);
        if (BF16OUT) Cb[(size_t)r * N + c] = (__bf16)v;
        else         Cf[(size_t)r * N + c] = v;
      }
    }
  }
}

// ---------------------------------------------------------------- pre panel: inline-LN + x@Wih^T (+bih+bhh)
static __device__ void pre_panel(SharedU& sh, int panel, const float* x,
                                 const float* lng, const float* lnb,
                                 const __bf16* wihb, const float* bih, const float* bhh,
                                 __bf16* preOut, int chunkRow0){
  const int tid = threadIdx.x, w = tid >> 6, l = tid & 63;
  const int r0 = panel * 128;
  for (int rr = 0; rr < 16; ++rr) {
    int rowl = w*16 + rr;
    const float* xr = x + (size_t)(chunkRow0 + r0 + rowl) * 512 + l*8;
    float4 v0 = *(const float4*)xr, v1 = *(const float4*)(xr + 4);
    float s  = v0.x+v0.y+v0.z+v0.w + v1.x+v1.y+v1.z+v1.w;
    float s2 = v0.x*v0.x+v0.y*v0.y+v0.z*v0.z+v0.w*v0.w + v1.x*v1.x+v1.y*v1.y+v1.z*v1.z+v1.w*v1.w;
    #pragma unroll
    for (int off = 1; off < 64; off <<= 1) { s += __shfl_xor(s, off); s2 += __shfl_xor(s2, off); }
    if (l == 0) {
      float mu = s * (1.f/512.f);
      float var = s2 * (1.f/512.f) - mu*mu;
      sh.g.stat[rowl] = mu; sh.g.stat[128 + rowl] = rsqrtf(var + 1e-5f);
    }
  }
  __syncthreads();
  for (int bn = 0; bn < 16; ++bn)
    tile_gemm<0,1,1,2>(sh, nullptr, x, lng, lnb, wihb, bih, bhh,
                       nullptr, preOut, chunkRow0 + r0, r0, bn, 2048, 512);
}

// ---------------------------------------------------------------- FFN+adapter panel (chunk-local rows)
static __device__ void ffn_panel(SharedU& sh, int panel, const __bf16* ymidb,
                                 const __bf16* m0bf, const float* m0b,
                                 const __bf16* m1bf, const float* m1b,
                                 __bf16* a1, float* y2,
                                 const __bf16* awT0, const __bf16* awT1,
                                 const float* ab0, const float* ab1){
  const int tid = threadIdx.x, w = tid >> 6, l = tid & 63;
  const int r0 = panel * 128;
  for (int bn = 0; bn < 16; ++bn)
    tile_gemm<1,1,0,0>(sh, ymidb, nullptr, nullptr, nullptr, m0bf, m0b, nullptr,
                       nullptr, a1, r0, r0, bn, 2048, 512);
  __syncthreads();
  for (int bn = 0; bn < 4; ++bn)
    tile_gemm<0,0,0,1>(sh, a1, nullptr, nullptr, nullptr, m1bf, m1b, nullptr,
                       y2, nullptr, r0, r0, bn, 512, 2048);
  __syncthreads();
  // adapter phase a: z = relu(y2 @ awT0 + ab0) into zl[128][64]
  const float bz = ab0[l];
  for (int rr = 0; rr < 16; ++rr) {
    int rowl = w*16 + rr; int row = r0 + rowl;
    const unsigned long long* yp = (const unsigned long long*)(void*)(y2 + (size_t)row * 512);
    float acc = bz;
    #pragma unroll 4
    for (int k2 = 0; k2 < 256; ++k2) {
      union { unsigned long long q; float f[2]; } z;
      z.q = __hip_atomic_load(yp + k2, __ATOMIC_RELAXED, __HIP_MEMORY_SCOPE_AGENT);
      acc += z.f[0]*(float)awT0[(k2*2)*64 + l] + z.f[1]*(float)awT0[(k2*2+1)*64 + l];
    }
    sh.zl[rowl*64 + l] = fmaxf(acc, 0.f);
  }
  __syncthreads();
  // adapter phase b: out = y2 + z@awT1 + ab1 + ymid  (in place on y2)
  for (int rr = 0; rr < 16; ++rr) {
    int rowl = w*16 + rr; int row = r0 + rowl;
    #pragma unroll
    for (int dd = 0; dd < 8; ++dd) {
      int d = dd*64 + l;
      float yv = __uint_as_float(__hip_atomic_load((const unsigned int*)(void*)(y2 + (size_t)row*512 + d),
                                                   __ATOMIC_RELAXED, __HIP_MEMORY_SCOPE_AGENT));
      float acc = ab1[d] + yv + (float)ymidb[(size_t)row*512 + d];
      #pragma unroll 4
      for (int j = 0; j < 64; ++j) acc += sh.zl[rowl*64 + j] * (float)awT1[j*512 + d];
      y2[(size_t)row*512 + d] = acc;
    }
  }
}

// ---------------------------------------------------------------- scan core (r6-proven packet protocol)
static __device__ void scan_core(SharedU& sh, int s,
    const __bf16* Whh, const __bf16* preC, const float* x, const void* firstp,
    const float* h0, const float* c0, float* cstate, __bf16* ymidbC,
    unsigned long long* HP, int mode, float* hout, float* cout, int tBase){
  const int tid = threadIdx.x, w = tid >> 6, l = tid & 63;
  const int d0 = s * 32;
  __bf16* Hl = sh.s.Hl; float* gl = sh.s.gl;

  bf16x8 wf[16];
  {
    int rl = w*16 + (l & 15);
    int gr = (rl >> 5) * 512 + d0 + (rl & 31);
    const __bf16* base = Whh + (size_t)gr * 512 + ((l >> 4) << 3);
    #pragma unroll
    for (int kt = 0; kt < 16; ++kt) wf[kt] = *(const bf16x8*)(void*)(base + kt*32);
  }
  const int b = tid >> 4, dl2 = (tid & 15) * 2;
  const int dg = d0 + dl2;
  const int opid = b * 256 + s * 16 + (tid & 15);

  float cr[2];
  if (tBase == 0) {
    float k0 = firstval(firstp, mode, b) ? 0.f : 1.f;
    float2 c2 = *(const float2*)(c0 + (size_t)b*512 + dg);
    cr[0] = c2.x * k0; cr[1] = c2.y * k0;
    float2 h = *(const float2*)(h0 + (size_t)b*512 + dg);
    unsigned long long pkt = (1ULL << 32) | (unsigned long long)pack2bf(h.x*k0, h.y*k0);
    __hip_atomic_store(HP + opid, pkt, __ATOMIC_RELAXED, __HIP_MEMORY_SCOPE_AGENT);
  } else {
    float2 c2 = *(const float2*)(cstate + (size_t)b*512 + dg);
    cr[0] = c2.x; cr[1] = c2.y;
  }

  for (int tl = 0; tl < TCH_; ++tl) {
    const int t = tBase + tl;
    const int rowg = t * 32 + b, rowl = tl * 32 + b;
    unsigned int pg[4];
    #pragma unroll
    for (int gi = 0; gi < 4; ++gi)
      pg[gi] = *(const unsigned int*)(void*)(preC + (size_t)rowl * 2048 + gi*512 + dg);
    float2 xv = *(const float2*)(x + (size_t)rowg * 512 + dg);
    const bool f_t1 = (t < T_-1) ? firstval(firstp, mode, rowg + 32) : false;

    const unsigned want = (unsigned)(t + 1);
    const unsigned long long* Pb = HP + ((size_t)(t & 1) << 13);
    unsigned long long pk[16];
    #pragma unroll
    for (int j = 0; j < 16; ++j)
      pk[j] = __hip_atomic_load(Pb + tid + (j << 9), __ATOMIC_RELAXED, __HIP_MEMORY_SCOPE_AGENT);
    while (true) {
      unsigned stale = 0;
      #pragma unroll
      for (int j = 0; j < 16; ++j)
        if ((unsigned)(pk[j] >> 32) != want) stale |= (1u << j);
      if (!stale) break;
      __builtin_amdgcn_s_sleep(1);
      #pragma unroll
      for (int j = 0; j < 16; ++j)
        if (stale & (1u << j))
          pk[j] = __hip_atomic_load(Pb + tid + (j << 9), __ATOMIC_RELAXED, __HIP_MEMORY_SCOPE_AGENT);
    }
    #pragma unroll
    for (int j = 0; j < 16; ++j) {
      int pid = tid + (j << 9);
      int pb = pid >> 8, ps = (pid >> 4) & 15, pi = pid & 15;
      int q = ps*32 + pi*2;
      *(unsigned int*)(void*)(Hl + pb*512 + (q ^ ((pb & 7) << 3))) = (unsigned)pk[j];
    }
    __syncthreads();

    f32x4 a0a = (f32x4){0.f,0.f,0.f,0.f}, a0b = (f32x4){0.f,0.f,0.f,0.f};
    f32x4 a1a = (f32x4){0.f,0.f,0.f,0.f}, a1b = (f32x4){0.f,0.f,0.f,0.f};
    #pragma unroll
    for (int kt = 0; kt < 16; kt += 2) {
      int ke0 = kt*32 + ((l >> 4) << 3), ke1 = (kt+1)*32 + ((l >> 4) << 3);
      int r0 = (l & 15), r1 = 16 + (l & 15);
      bf16x8 h00 = *(const bf16x8*)(void*)(Hl + r0*512 + (ke0 ^ ((r0 & 7) << 3)));
      bf16x8 h01 = *(const bf16x8*)(void*)(Hl + r0*512 + (ke1 ^ ((r0 & 7) << 3)));
      bf16x8 h10 = *(const bf16x8*)(void*)(Hl + r1*512 + (ke0 ^ ((r1 & 7) << 3)));
      bf16x8 h11 = *(const bf16x8*)(void*)(Hl + r1*512 + (ke1 ^ ((r1 & 7) << 3)));
      a0a = __builtin_amdgcn_mfma_f32_16x16x32_bf16(h00, wf[kt],   a0a, 0, 0, 0);
      a0b = __builtin_amdgcn_mfma_f32_16x16x32_bf16(h01, wf[kt+1], a0b, 0, 0, 0);
      a1a = __builtin_amdgcn_mfma_f32_16x16x32_bf16(h10, wf[kt],   a1a, 0, 0, 0);
      a1b = __builtin_amdgcn_mfma_f32_16x16x32_bf16(h11, wf[kt+1], a1b, 0, 0, 0);
    }
    f32x4 acc0 = a0a + a0b, acc1 = a1a + a1b;
    {
      int col = w*16 + (l & 15);
      #pragma unroll
      for (int j = 0; j < 4; ++j) {
        gl[(((l >> 4) << 2) + j) * 132 + col]        = acc0[j];
        gl[((16 + ((l >> 4) << 2) + j)) * 132 + col] = acc1[j];
      }
    }
    __syncthreads();

    float2 gv[4];
    #pragma unroll
    for (int gi = 0; gi < 4; ++gi) gv[gi] = *(const float2*)(gl + b*132 + gi*32 + dl2);
    const float keep1 = f_t1 ? 0.f : 1.f;
    float hh[2], cc[2];
    #pragma unroll
    for (int p = 0; p < 2; ++p) {
      float gi_ = (p ? gv[0].y : gv[0].x) + (p ? bfhi(pg[0]) : bflo(pg[0]));
      float gf_ = (p ? gv[1].y : gv[1].x) + (p ? bfhi(pg[1]) : bflo(pg[1]));
      float gg_ = (p ? gv[2].y : gv[2].x) + (p ? bfhi(pg[2]) : bflo(pg[2]));
      float go_ = (p ? gv[3].y : gv[3].x) + (p ? bfhi(pg[3]) : bflo(pg[3]));
      float cn = sigm(gf_) * cr[p] + sigm(gi_) * tanh_(gg_);
      float h  = sigm(go_) * tanh_(cn);
      cc[p] = cn; hh[p] = h;
    }
    cr[0] = cc[0] * keep1; cr[1] = cc[1] * keep1;
    float2 yv = { hh[0] + xv.x, hh[1] + xv.y };
    if (t < T_-1) {
      unsigned long long pkt = (((unsigned long long)(unsigned)(t + 2)) << 32)
                             | (unsigned long long)pack2bf(hh[0]*keep1, hh[1]*keep1);
      __hip_atomic_store(HP + (((size_t)((t+1) & 1)) << 13) + opid, pkt,
                         __ATOMIC_RELAXED, __HIP_MEMORY_SCOPE_AGENT);
      if (tl == TCH_-1) *(float2*)(cstate + (size_t)b*512 + dg) = make_float2(cr[0], cr[1]);
    } else {
      *(float2*)(hout + (size_t)b*512 + dg) = make_float2(hh[0], hh[1]);
      *(float2*)(cout + (size_t)b*512 + dg) = make_float2(cc[0], cc[1]);
    }
    *(unsigned int*)(void*)(ymidbC + (size_t)rowl * 512 + dg) = pack2bf(yv.x, yv.y);
  }
}

// ---------------------------------------------------------------- fused: scan (0-15) | FFN c-1 (16-79) | pre c+1 (80-143)
__global__ __launch_bounds__(512) void fused_scan(
    const __bf16* __restrict__ Whh, const __bf16* __restrict__ preCur,
    const float* __restrict__ x, const void* __restrict__ firstp,
    const float* __restrict__ h0, const float* __restrict__ c0,
    float* __restrict__ cstate, __bf16* __restrict__ ymidbCur,
    unsigned long long* __restrict__ HP, const unsigned int* __restrict__ modep,
    float* __restrict__ hout, float* __restrict__ cout, int tBase,
    int doFfn, const __bf16* __restrict__ ymidbPrev,
    const __bf16* __restrict__ m0bf, const float* __restrict__ m0b,
    const __bf16* __restrict__ m1bf, const float* __restrict__ m1b,
    __bf16* __restrict__ a1, float* __restrict__ outPrev,
    const __bf16* __restrict__ awT0, const __bf16* __restrict__ awT1,
    const float* __restrict__ ab0, const float* __restrict__ ab1,
    int doPre, const float* __restrict__ lng, const float* __restrict__ lnb,
    const __bf16* __restrict__ wihb, const float* __restrict__ bih, const float* __restrict__ bhh,
    __bf16* __restrict__ preNext, int nextRow0){
  __shared__ SharedU sh;
  const int bid = blockIdx.x;
  if (bid < 16) {
    scan_core(sh, bid, Whh, preCur, x, firstp, h0, c0, cstate, ymidbCur,
              HP, (int)*modep, hout, cout, tBase);
  } else if (bid < 80) {
    if (!doFfn) return;
    ffn_panel(sh, bid - 16, ymidbPrev, m0bf, m0b, m1bf, m1b, a1, outPrev,
              awT0, awT1, ab0, ab1);
  } else if (bid < 144) {
    if (!doPre) return;
    pre_panel(sh, bid - 80, x, lng, lnb, wihb, bih, bhh, preNext, nextRow0);
  }
}

// ---------------------------------------------------------------- standalone panel kernels (edges / Plan C)
__global__ __launch_bounds__(512) void pre_kernel(
    const float* __restrict__ x, const float* __restrict__ lng, const float* __restrict__ lnb,
    const __bf16* __restrict__ wihb, const float* __restrict__ bih, const float* __restrict__ bhh,
    __bf16* __restrict__ preOut, int chunkRow0){
  __shared__ SharedU sh;
  pre_panel(sh, blockIdx.x, x, lng, lnb, wihb, bih, bhh, preOut, chunkRow0);
}

__global__ __launch_bounds__(512) void ffn_kernel(
    const __bf16* __restrict__ ymidb,
    const __bf16* __restrict__ m0bf, const float* __restrict__ m0b,
    const __bf16* __restrict__ m1bf, const float* __restrict__ m1b,
    __bf16* __restrict__ a1, float* __restrict__ y2,
    const __bf16* __restrict__ awT0, const __bf16* __restrict__ awT1,
    const float* __restrict__ ab0, const float* __restrict__ ab1){
  __shared__ SharedU sh;
  ffn_panel(sh, blockIdx.x, ymidb, m0bf, m0b, m1bf, m1b, a1, y2, awT0, awT1, ab0, ab1);
}

// ---------------------------------------------------------------- launch
extern "C" void kernel_launch(void* const* d_in, const int* in_sizes, int n_in,
                              void* d_out, int out_size, void* d_ws, size_t ws_size,
                              hipStream_t stream){
  (void)in_sizes; (void)n_in; (void)out_size;
  const float* x    = (const float*)d_in[0];
  const void*  first=               d_in[1];
  const float* h0   = (const float*)d_in[2];
  const float* c0   = (const float*)d_in[3];
  const float* ln_g = (const float*)d_in[4];
  const float* ln_b = (const float*)d_in[5];
  const float* Wih  = (const float*)d_in[6];
  const float* Whh  = (const float*)d_in[7];
  const float* bih  = (const float*)d_in[8];
  const float* bhh  = (const float*)d_in[9];
  const float* m0w  = (const float*)d_in[10];
  const float* m0b  = (const float*)d_in[11];
  const float* m1w  = (const float*)d_in[12];
  const float* m1b  = (const float*)d_in[13];
  const float* aw0  = (const float*)d_in[14];
  const float* ab0  = (const float*)d_in[15];
  const float* aw1  = (const float*)d_in[16];
  const float* ab1  = (const float*)d_in[17];

  float* out  = (float*)d_out;
  float* hout = out + (size_t)TB_ * D_;
  float* cout = hout + B_ * D_;
  char* ws = (char*)d_ws;

  const bool planA = (ws_size >= (size_t)126160000ULL);

  if (planA) {
    // Plan A: overlap layout (~126.2 MB)
    __bf16* preA  = (__bf16*)(ws + 0LL);
    __bf16* preB  = (__bf16*)(ws + 33554432LL);
    __bf16* a1b   = (__bf16*)(ws + 67108864LL);
    __bf16* ymA   = (__bf16*)(ws + 100663296LL);
    __bf16* ymB   = (__bf16*)(ws + 109051904LL);
    __bf16* wihb  = (__bf16*)(ws + 117440512LL);
    __bf16* whhb  = (__bf16*)(ws + 119537664LL);
    __bf16* m0bf  = (__bf16*)(ws + 121634816LL);
    __bf16* m1bf  = (__bf16*)(ws + 123731968LL);
    __bf16* awT0  = (__bf16*)(ws + 125829120LL);
    __bf16* awT1  = (__bf16*)(ws + 125894656LL);
    unsigned long long* HP = (unsigned long long*)(ws + 125960192LL);
    float*  cstate= (float*) (ws + 126091264LL);
    unsigned int* mode = (unsigned int*)(ws + 126156800LL);

    hipMemsetAsync(HP, 0, 131072, stream);
    detect_first_kernel<<<1, 256, 0, stream>>>((const unsigned char*)first, mode);
    convert_w_kernel<<<4352, 256, 0, stream>>>(Wih, Whh, m0w, m1w, aw0, aw1,
                                               wihb, whhb, m0bf, m1bf, awT0, awT1);
    pre_kernel<<<64, 512, 0, stream>>>(x, ln_g, ln_b, wihb, bih, bhh, preA, 0);
    for (int c = 0; c < 4; ++c) {
      __bf16* preCur  = (c & 1) ? preB : preA;
      __bf16* preNext = (c & 1) ? preA : preB;
      __bf16* ymCur   = (c & 1) ? ymB : ymA;
      __bf16* ymPrev  = (c & 1) ? ymA : ymB;
      int doFfn = (c > 0), doPre = (c < 3);
      fused_scan<<<144, 512, 0, stream>>>(
          whhb, preCur, x, first, h0, c0, cstate, ymCur, HP, mode, hout, cout, c * TCH_,
          doFfn, ymPrev, m0bf, m0b, m1bf, m1b, a1b, out + (size_t)(c-1) * RCH_ * D_,
          awT0, awT1, ab0, ab1,
          doPre, ln_g, ln_b, wihb, bih, bhh, preNext, (c+1) * RCH_);
    }
    ffn_kernel<<<64, 512, 0, stream>>>(ymB, m0bf, m0b, m1bf, m1b, a1b,
                                       out + (size_t)3 * RCH_ * D_, awT0, awT1, ab0, ab1);
  } else {
    // Plan C: serial layout (~50.7 MB); a1 aliases pre (dead after scan)
    __bf16* preS  = (__bf16*)(ws + 0LL);
    __bf16* a1b   = preS;
    __bf16* ymC   = (__bf16*)(ws + 33554432LL);
    __bf16* wihb  = (__bf16*)(ws + 41943040LL);
    __bf16* whhb  = (__bf16*)(ws + 44040192LL);
    __bf16* m0bf  = (__bf16*)(ws + 46137344LL);
    __bf16* m1bf  = (__bf16*)(ws + 48234496LL);
    __bf16* awT0  = (__bf16*)(ws + 50331648LL);
    __bf16* awT1  = (__bf16*)(ws + 50397184LL);
    unsigned long long* HP = (unsigned long long*)(ws + 50462720LL);
    float*  cstate= (float*) (ws + 50593792LL);
    unsigned int* mode = (unsigned int*)(ws + 50659328LL);

    hipMemsetAsync(HP, 0, 131072, stream);
    detect_first_kernel<<<1, 256, 0, stream>>>((const unsigned char*)first, mode);
    convert_w_kernel<<<4352, 256, 0, stream>>>(Wih, Whh, m0w, m1w, aw0, aw1,
                                               wihb, whhb, m0bf, m1bf, awT0, awT1);
    for (int c = 0; c < 4; ++c) {
      pre_kernel<<<64, 512, 0, stream>>>(x, ln_g, ln_b, wihb, bih, bhh, preS, c * RCH_);
      fused_scan<<<16, 512, 0, stream>>>(
          whhb, preS, x, first, h0, c0, cstate, ymC, HP, mode, hout, cout, c * TCH_,
          0, nullptr, nullptr, nullptr, nullptr, nullptr, nullptr, nullptr,
          nullptr, nullptr, nullptr, nullptr,
          0, nullptr, nullptr, nullptr, nullptr, nullptr, nullptr, 0);
      ffn_kernel<<<64, 512, 0, stream>>>(ymC, m0bf, m0b, m1bf, m1b, a1b,
                                         out + (size_t)c * RCH_ * D_, awT0, awT1, ab0, ab1);
    }
  }
}

// Round 11
// 6717.271 us; speedup vs baseline: 1.0446x; 1.0263x over previous
//
#include <hip/hip_runtime.h>

#define T_ 1024
#define B_ 32
#define D_ 512
#define FF_ 2048
#define TB_ 32768   // T_*B_
#define TCH_ 256    // T chunk
#define RCH_ 8192   // TCH_*B_ rows per chunk

typedef short bf16x8 __attribute__((ext_vector_type(8)));
typedef float f32x4 __attribute__((ext_vector_type(4)));

union SharedU {
  struct { __bf16 Hl[32*512]; float gl[32*132]; } s;            // scan: 49664 B
  struct { __bf16 As[128*64]; __bf16 Bs[128*64]; float stat[256]; } g; // gemm: 33792 B
  float zl[128*64];                                              // adapter: 32768 B
};

static __device__ __forceinline__ unsigned int pack2bf(float a, float b){
  union { __bf16 h[2]; unsigned int u; } z;
  z.h[0] = (__bf16)a; z.h[1] = (__bf16)b; return z.u;
}
static __device__ __forceinline__ float bflo(unsigned int u){ return __uint_as_float(u<<16); }
static __device__ __forceinline__ float bfhi(unsigned int u){ return __uint_as_float(u & 0xffff0000u); }
static __device__ __forceinline__ float sigm(float x){ return 1.f/(1.f+__expf(-x)); }
static __device__ __forceinline__ float tanh_(float x){ return 1.f - 2.f/(1.f+__expf(2.f*x)); }

static __device__ __forceinline__ bool firstval(const void* p, int mode, int idx){
  return mode ? (((const int*)p)[idx] != 0) : (((const unsigned char*)p)[idx] != 0);
}

// ---------------------------------------------------------------- detect bool dtype
__global__ void detect_first_kernel(const unsigned char* __restrict__ p, unsigned int* __restrict__ mode){
  __shared__ int found;
  if (threadIdx.x == 0) found = 0;
  __syncthreads();
  int f = 0;
  for (int i = threadIdx.x; i < TB_; i += 256) if ((i & 3) != 0 && p[i] != 0) f = 1;
  if (f) atomicAdd(&found, 1);
  __syncthreads();
  if (threadIdx.x == 0) *mode = (found == 0) ? 1u : 0u;
}

// ---------------------------------------------------------------- weight conversion
__global__ void convert_w_kernel(const float* __restrict__ Wih, const float* __restrict__ Whh,
                                 const float* __restrict__ m0w, const float* __restrict__ m1w,
                                 const float* __restrict__ aw0, const float* __restrict__ aw1,
                                 __bf16* __restrict__ Wihb, __bf16* __restrict__ Whhb,
                                 __bf16* __restrict__ m0b,  __bf16* __restrict__ m1b,
                                 __bf16* __restrict__ awT0, __bf16* __restrict__ awT1){
  int bid = blockIdx.x;
  if (bid < 4096) {
    int ai = bid >> 10;
    size_t off = (size_t)(bid & 1023) * 1024 + threadIdx.x * 4;
    const float* src = (ai==0)?Wih:(ai==1)?Whh:(ai==2)?m0w:m1w;
    __bf16* dst = (ai==0)?Wihb:(ai==1)?Whhb:(ai==2)?m0b:m1b;
    float4 v = *(const float4*)(src + off);
    union { __bf16 h[4]; uint2 u; } z;
    z.h[0]=(__bf16)v.x; z.h[1]=(__bf16)v.y; z.h[2]=(__bf16)v.z; z.h[3]=(__bf16)v.w;
    *(uint2*)(void*)(dst + off) = z.u;
  } else {
    int e = (bid - 4096) * 256 + threadIdx.x;
    if (e < 32768) { int k = e >> 6, j = e & 63;  awT0[e] = (__bf16)aw0[j*512 + k]; }
    else { int e2 = e - 32768; int j = e2 >> 9, d = e2 & 511; awT1[e2] = (__bf16)aw1[d*64 + j]; }
  }
}

// ---------------------------------------------------------------- 512-thread 128x128 tile GEMM
// AMODE: 0 = bf16 A plain loads (same-WG RAW is L1-coherent after __syncthreads);
//        2 = A from f32 x with inline LayerNorm (stats in stat[], params lng/lnb)
template<int RELU,int BF16OUT,int TWOBIAS,int AMODE>
static __device__ void tile_gemm(SharedU& sh,
    const __bf16* A, const float* Ax, const float* lng, const float* lnb,
    const __bf16* W, const float* bias0, const float* bias1,
    float* Cf, __bf16* Cb, int aRow0, int cRow0, int bn, int N, int K){
  __bf16* As = sh.g.As; __bf16* Bs = sh.g.Bs; const float* stat = sh.g.stat;
  const int tid = threadIdx.x, w = tid >> 6, l = tid & 63;
  const int wm = (w >> 2) * 64, wn = (w & 3) * 32;
  const int nk = K >> 6;
  uint4 ra[2], rb[2];
  float4 rx[2][2];
  #pragma unroll
  for (int i = 0; i < 2; ++i) {
    int s = tid + (i << 9); int row = s >> 3; int ks = s & 7;
    if (AMODE == 2) {
      const float* px = Ax + (size_t)(aRow0 + row) * 512 + ks*8;
      rx[i][0] = *(const float4*)px; rx[i][1] = *(const float4*)(px + 4);
    } else {
      ra[i] = *(const uint4*)(void*)(A + (size_t)(aRow0 + row) * K + ks*8);
    }
    rb[i] = *(const uint4*)(void*)(W + (size_t)(bn*128 + row) * K + ks*8);
  }
  f32x4 acc[4][2];
  #pragma unroll
  for (int mt = 0; mt < 4; ++mt)
    #pragma unroll
    for (int nt = 0; nt < 2; ++nt) acc[mt][nt] = (f32x4){0.f,0.f,0.f,0.f};

  for (int kt = 0; kt < nk; ++kt) {
    __syncthreads();
    #pragma unroll
    for (int i = 0; i < 2; ++i) {
      int s = tid + (i << 9); int row = s >> 3; int ks = s & 7;
      int wi = row * 64 + ((ks * 8) ^ ((row & 7) << 3));
      if (AMODE == 2) {
        float mu = stat[row], rs = stat[128 + row];
        int col = kt*64 + ks*8;
        float4 g0 = *(const float4*)(lng + col), g1 = *(const float4*)(lng + col + 4);
        float4 b0 = *(const float4*)(lnb + col), b1 = *(const float4*)(lnb + col + 4);
        union { __bf16 h[8]; uint4 u; } z;
        z.h[0]=(__bf16)((rx[i][0].x-mu)*rs*g0.x+b0.x); z.h[1]=(__bf16)((rx[i][0].y-mu)*rs*g0.y+b0.y);
        z.h[2]=(__bf16)((rx[i][0].z-mu)*rs*g0.z+b0.z); z.h[3]=(__bf16)((rx[i][0].w-mu)*rs*g0.w+b0.w);
        z.h[4]=(__bf16)((rx[i][1].x-mu)*rs*g1.x+b1.x); z.h[5]=(__bf16)((rx[i][1].y-mu)*rs*g1.y+b1.y);
        z.h[6]=(__bf16)((rx[i][1].z-mu)*rs*g1.z+b1.z); z.h[7]=(__bf16)((rx[i][1].w-mu)*rs*g1.w+b1.w);
        *(uint4*)(void*)(As + wi) = z.u;
      } else {
        *(uint4*)(void*)(As + wi) = ra[i];
      }
      *(uint4*)(void*)(Bs + wi) = rb[i];
    }
    __syncthreads();
    if (kt + 1 < nk) {
      #pragma unroll
      for (int i = 0; i < 2; ++i) {
        int s = tid + (i << 9); int row = s >> 3; int ks = s & 7;
        if (AMODE == 2) {
          const float* px = Ax + (size_t)(aRow0 + row) * 512 + (kt+1)*64 + ks*8;
          rx[i][0] = *(const float4*)px; rx[i][1] = *(const float4*)(px + 4);
        } else {
          ra[i] = *(const uint4*)(void*)(A + (size_t)(aRow0 + row) * K + (kt+1)*64 + ks*8);
        }
        rb[i] = *(const uint4*)(void*)(W + (size_t)(bn*128 + row) * K + (kt+1)*64 + ks*8);
      }
    }
    #pragma unroll
    for (int kk = 0; kk < 2; ++kk) {
      bf16x8 af[4], bfv[2];
      const int ke = kk * 32 + ((l >> 4) << 3);
      #pragma unroll
      for (int mt = 0; mt < 4; ++mt) {
        int row = wm + mt*16 + (l & 15);
        af[mt] = *(const bf16x8*)(void*)(As + row*64 + (ke ^ ((row & 7) << 3)));
      }
      #pragma unroll
      for (int nt = 0; nt < 2; ++nt) {
        int row = wn + nt*16 + (l & 15);
        bfv[nt] = *(const bf16x8*)(void*)(Bs + row*64 + (ke ^ ((row & 7) << 3)));
      }
      #pragma unroll
      for (int mt = 0; mt < 4; ++mt)
        #pragma unroll
        for (int nt = 0; nt < 2; ++nt)
          acc[mt][nt] = __builtin_amdgcn_mfma_f32_16x16x32_bf16(af[mt], bfv[nt], acc[mt][nt], 0, 0, 0);
    }
  }
  #pragma unroll
  for (int nt = 0; nt < 2; ++nt) {
    int c = bn*128 + wn + nt*16 + (l & 15);
    float bv = bias0[c];
    if (TWOBIAS) bv += bias1[c];
    #pragma unroll
    for (int mt = 0; mt < 4; ++mt) {
      #pragma unroll
      for (int j = 0; j < 4; ++j) {
        int r = cRow0 + wm + mt*16 + ((l >> 4) << 2) + j;
        float v = acc[mt][nt][j] + bv;
        if (RELU) v = fmaxf(v, 0.f);
        if (BF16OUT) Cb[(size_t)r * N + c] = (__bf16)v;
        else         Cf[(size_t)r * N + c] = v;
      }
    }
  }
}

// ---------------------------------------------------------------- pre panel: inline-LN + x@Wih^T (+bih+bhh)
static __device__ void pre_panel(SharedU& sh, int panel, const float* x,
                                 const float* lng, const float* lnb,
                                 const __bf16* wihb, const float* bih, const float* bhh,
                                 __bf16* preOut, int chunkRow0){
  const int tid = threadIdx.x, w = tid >> 6, l = tid & 63;
  const int r0 = panel * 128;
  for (int rr = 0; rr < 16; ++rr) {
    int rowl = w*16 + rr;
    const float* xr = x + (size_t)(chunkRow0 + r0 + rowl) * 512 + l*8;
    float4 v0 = *(const float4*)xr, v1 = *(const float4*)(xr + 4);
    float s  = v0.x+v0.y+v0.z+v0.w + v1.x+v1.y+v1.z+v1.w;
    float s2 = v0.x*v0.x+v0.y*v0.y+v0.z*v0.z+v0.w*v0.w + v1.x*v1.x+v1.y*v1.y+v1.z*v1.z+v1.w*v1.w;
    #pragma unroll
    for (int off = 1; off < 64; off <<= 1) { s += __shfl_xor(s, off); s2 += __shfl_xor(s2, off); }
    if (l == 0) {
      float mu = s * (1.f/512.f);
      float var = s2 * (1.f/512.f) - mu*mu;
      sh.g.stat[rowl] = mu; sh.g.stat[128 + rowl] = rsqrtf(var + 1e-5f);
    }
  }
  __syncthreads();
  for (int bn = 0; bn < 16; ++bn)
    tile_gemm<0,1,1,2>(sh, nullptr, x, lng, lnb, wihb, bih, bhh,
                       nullptr, preOut, chunkRow0 + r0, r0, bn, 2048, 512);
}

// ---------------------------------------------------------------- FFN+adapter panel (chunk-local rows)
// All RAW hazards are same-WG (ffn1 writes its full a1 slab before ffn2 reads it; y2
// likewise) -> plain loads are L1-coherent after __syncthreads (vmcnt drain).
static __device__ void ffn_panel(SharedU& sh, int panel, const __bf16* ymidb,
                                 const __bf16* m0bf, const float* m0b,
                                 const __bf16* m1bf, const float* m1b,
                                 __bf16* a1, float* y2,
                                 const __bf16* awT0, const __bf16* awT1,
                                 const float* ab0, const float* ab1){
  const int tid = threadIdx.x, w = tid >> 6, l = tid & 63;
  const int r0 = panel * 128;
  for (int bn = 0; bn < 16; ++bn)
    tile_gemm<1,1,0,0>(sh, ymidb, nullptr, nullptr, nullptr, m0bf, m0b, nullptr,
                       nullptr, a1, r0, r0, bn, 2048, 512);
  __syncthreads();
  for (int bn = 0; bn < 4; ++bn)
    tile_gemm<0,0,0,0>(sh, a1, nullptr, nullptr, nullptr, m1bf, m1b, nullptr,
                       y2, nullptr, r0, r0, bn, 512, 2048);
  __syncthreads();
  // adapter phase a: z = relu(y2 @ awT0 + ab0) into zl[128][64]  (plain float4 loads)
  const float bz = ab0[l];
  for (int rr = 0; rr < 16; ++rr) {
    int rowl = w*16 + rr; int row = r0 + rowl;
    const float* yr = y2 + (size_t)row * 512;
    float acc = bz;
    #pragma unroll 4
    for (int k = 0; k < 512; k += 4) {
      float4 v = *(const float4*)(yr + k);
      acc += v.x*(float)awT0[(k+0)*64 + l] + v.y*(float)awT0[(k+1)*64 + l]
           + v.z*(float)awT0[(k+2)*64 + l] + v.w*(float)awT0[(k+3)*64 + l];
    }
    sh.zl[rowl*64 + l] = fmaxf(acc, 0.f);
  }
  __syncthreads();
  // adapter phase b: out = y2 + z@awT1 + ab1 + ymid  (in place on y2; per-thread element)
  for (int rr = 0; rr < 16; ++rr) {
    int rowl = w*16 + rr; int row = r0 + rowl;
    #pragma unroll
    for (int dd = 0; dd < 8; ++dd) {
      int d = dd*64 + l;
      float acc = ab1[d] + y2[(size_t)row*512 + d] + (float)ymidb[(size_t)row*512 + d];
      #pragma unroll 4
      for (int j = 0; j < 64; ++j) acc += sh.zl[rowl*64 + j] * (float)awT1[j*512 + d];
      y2[(size_t)row*512 + d] = acc;
    }
  }
}

// ---------------------------------------------------------------- scan core (r6-proven packet protocol)
static __device__ void scan_core(SharedU& sh, int s,
    const __bf16* Whh, const __bf16* preC, const float* x, const void* firstp,
    const float* h0, const float* c0, float* cstate, __bf16* ymidbC,
    unsigned long long* HP, int mode, float* hout, float* cout, int tBase){
  const int tid = threadIdx.x, w = tid >> 6, l = tid & 63;
  const int d0 = s * 32;
  __bf16* Hl = sh.s.Hl; float* gl = sh.s.gl;

  bf16x8 wf[16];
  {
    int rl = w*16 + (l & 15);
    int gr = (rl >> 5) * 512 + d0 + (rl & 31);
    const __bf16* base = Whh + (size_t)gr * 512 + ((l >> 4) << 3);
    #pragma unroll
    for (int kt = 0; kt < 16; ++kt) wf[kt] = *(const bf16x8*)(void*)(base + kt*32);
  }
  const int b = tid >> 4, dl2 = (tid & 15) * 2;
  const int dg = d0 + dl2;
  const int opid = b * 256 + s * 16 + (tid & 15);

  float cr[2];
  if (tBase == 0) {
    float k0 = firstval(firstp, mode, b) ? 0.f : 1.f;
    float2 c2 = *(const float2*)(c0 + (size_t)b*512 + dg);
    cr[0] = c2.x * k0; cr[1] = c2.y * k0;
    float2 h = *(const float2*)(h0 + (size_t)b*512 + dg);
    unsigned long long pkt = (1ULL << 32) | (unsigned long long)pack2bf(h.x*k0, h.y*k0);
    __hip_atomic_store(HP + opid, pkt, __ATOMIC_RELAXED, __HIP_MEMORY_SCOPE_AGENT);
  } else {
    float2 c2 = *(const float2*)(cstate + (size_t)b*512 + dg);
    cr[0] = c2.x; cr[1] = c2.y;
  }

  for (int tl = 0; tl < TCH_; ++tl) {
    const int t = tBase + tl;
    const int rowg = t * 32 + b, rowl = tl * 32 + b;
    unsigned int pg[4];
    #pragma unroll
    for (int gi = 0; gi < 4; ++gi)
      pg[gi] = *(const unsigned int*)(void*)(preC + (size_t)rowl * 2048 + gi*512 + dg);
    float2 xv = *(const float2*)(x + (size_t)rowg * 512 + dg);
    const bool f_t1 = (t < T_-1) ? firstval(firstp, mode, rowg + 32) : false;

    const unsigned want = (unsigned)(t + 1);
    const unsigned long long* Pb = HP + ((size_t)(t & 1) << 13);
    unsigned long long pk[16];
    #pragma unroll
    for (int j = 0; j < 16; ++j)
      pk[j] = __hip_atomic_load(Pb + tid + (j << 9), __ATOMIC_RELAXED, __HIP_MEMORY_SCOPE_AGENT);
    while (true) {
      unsigned stale = 0;
      #pragma unroll
      for (int j = 0; j < 16; ++j)
        if ((unsigned)(pk[j] >> 32) != want) stale |= (1u << j);
      if (!stale) break;
      __builtin_amdgcn_s_sleep(1);
      #pragma unroll
      for (int j = 0; j < 16; ++j)
        if (stale & (1u << j))
          pk[j] = __hip_atomic_load(Pb + tid + (j << 9), __ATOMIC_RELAXED, __HIP_MEMORY_SCOPE_AGENT);
    }
    #pragma unroll
    for (int j = 0; j < 16; ++j) {
      int pid = tid + (j << 9);
      int pb = pid >> 8, ps = (pid >> 4) & 15, pi = pid & 15;
      int q = ps*32 + pi*2;
      *(unsigned int*)(void*)(Hl + pb*512 + (q ^ ((pb & 7) << 3))) = (unsigned)pk[j];
    }
    __syncthreads();

    f32x4 a0a = (f32x4){0.f,0.f,0.f,0.f}, a0b = (f32x4){0.f,0.f,0.f,0.f};
    f32x4 a1a = (f32x4){0.f,0.f,0.f,0.f}, a1b = (f32x4){0.f,0.f,0.f,0.f};
    #pragma unroll
    for (int kt = 0; kt < 16; kt += 2) {
      int ke0 = kt*32 + ((l >> 4) << 3), ke1 = (kt+1)*32 + ((l >> 4) << 3);
      int r0 = (l & 15), r1 = 16 + (l & 15);
      bf16x8 h00 = *(const bf16x8*)(void*)(Hl + r0*512 + (ke0 ^ ((r0 & 7) << 3)));
      bf16x8 h01 = *(const bf16x8*)(void*)(Hl + r0*512 + (ke1 ^ ((r0 & 7) << 3)));
      bf16x8 h10 = *(const bf16x8*)(void*)(Hl + r1*512 + (ke0 ^ ((r1 & 7) << 3)));
      bf16x8 h11 = *(const bf16x8*)(void*)(Hl + r1*512 + (ke1 ^ ((r1 & 7) << 3)));
      a0a = __builtin_amdgcn_mfma_f32_16x16x32_bf16(h00, wf[kt],   a0a, 0, 0, 0);
      a0b = __builtin_amdgcn_mfma_f32_16x16x32_bf16(h01, wf[kt+1], a0b, 0, 0, 0);
      a1a = __builtin_amdgcn_mfma_f32_16x16x32_bf16(h10, wf[kt],   a1a, 0, 0, 0);
      a1b = __builtin_amdgcn_mfma_f32_16x16x32_bf16(h11, wf[kt+1], a1b, 0, 0, 0);
    }
    f32x4 acc0 = a0a + a0b, acc1 = a1a + a1b;
    {
      int col = w*16 + (l & 15);
      #pragma unroll
      for (int j = 0; j < 4; ++j) {
        gl[(((l >> 4) << 2) + j) * 132 + col]        = acc0[j];
        gl[((16 + ((l >> 4) << 2) + j)) * 132 + col] = acc1[j];
      }
    }
    __syncthreads();

    float2 gv[4];
    #pragma unroll
    for (int gi = 0; gi < 4; ++gi) gv[gi] = *(const float2*)(gl + b*132 + gi*32 + dl2);
    const float keep1 = f_t1 ? 0.f : 1.f;
    float hh[2], cc[2];
    #pragma unroll
    for (int p = 0; p < 2; ++p) {
      float gi_ = (p ? gv[0].y : gv[0].x) + (p ? bfhi(pg[0]) : bflo(pg[0]));
      float gf_ = (p ? gv[1].y : gv[1].x) + (p ? bfhi(pg[1]) : bflo(pg[1]));
      float gg_ = (p ? gv[2].y : gv[2].x) + (p ? bfhi(pg[2]) : bflo(pg[2]));
      float go_ = (p ? gv[3].y : gv[3].x) + (p ? bfhi(pg[3]) : bflo(pg[3]));
      float cn = sigm(gf_) * cr[p] + sigm(gi_) * tanh_(gg_);
      float h  = sigm(go_) * tanh_(cn);
      cc[p] = cn; hh[p] = h;
    }
    cr[0] = cc[0] * keep1; cr[1] = cc[1] * keep1;
    float2 yv = { hh[0] + xv.x, hh[1] + xv.y };
    if (t < T_-1) {
      unsigned long long pkt = (((unsigned long long)(unsigned)(t + 2)) << 32)
                             | (unsigned long long)pack2bf(hh[0]*keep1, hh[1]*keep1);
      __hip_atomic_store(HP + (((size_t)((t+1) & 1)) << 13) + opid, pkt,
                         __ATOMIC_RELAXED, __HIP_MEMORY_SCOPE_AGENT);
      if (tl == TCH_-1) *(float2*)(cstate + (size_t)b*512 + dg) = make_float2(cr[0], cr[1]);
    } else {
      *(float2*)(hout + (size_t)b*512 + dg) = make_float2(hh[0], hh[1]);
      *(float2*)(cout + (size_t)b*512 + dg) = make_float2(cc[0], cc[1]);
    }
    *(unsigned int*)(void*)(ymidbC + (size_t)rowl * 512 + dg) = pack2bf(yv.x, yv.y);
  }
}

// ---------------------------------------------------------------- fused: scan (0-15) | FFN c-1 (16-79) | pre c+1 (80-143)
__global__ __launch_bounds__(512) void fused_scan(
    const __bf16* __restrict__ Whh, const __bf16* __restrict__ preCur,
    const float* __restrict__ x, const void* __restrict__ firstp,
    const float* __restrict__ h0, const float* __restrict__ c0,
    float* __restrict__ cstate, __bf16* __restrict__ ymidbCur,
    unsigned long long* __restrict__ HP, const unsigned int* __restrict__ modep,
    float* __restrict__ hout, float* __restrict__ cout, int tBase,
    int doFfn, const __bf16* __restrict__ ymidbPrev,
    const __bf16* __restrict__ m0bf, const float* __restrict__ m0b,
    const __bf16* __restrict__ m1bf, const float* __restrict__ m1b,
    __bf16* __restrict__ a1, float* __restrict__ outPrev,
    const __bf16* __restrict__ awT0, const __bf16* __restrict__ awT1,
    const float* __restrict__ ab0, const float* __restrict__ ab1,
    int doPre, const float* __restrict__ lng, const float* __restrict__ lnb,
    const __bf16* __restrict__ wihb, const float* __restrict__ bih, const float* __restrict__ bhh,
    __bf16* __restrict__ preNext, int nextRow0){
  __shared__ SharedU sh;
  const int bid = blockIdx.x;
  if (bid < 16) {
    scan_core(sh, bid, Whh, preCur, x, firstp, h0, c0, cstate, ymidbCur,
              HP, (int)*modep, hout, cout, tBase);
  } else if (bid < 80) {
    if (!doFfn) return;
    ffn_panel(sh, bid - 16, ymidbPrev, m0bf, m0b, m1bf, m1b, a1, outPrev,
              awT0, awT1, ab0, ab1);
  } else if (bid < 144) {
    if (!doPre) return;
    pre_panel(sh, bid - 80, x, lng, lnb, wihb, bih, bhh, preNext, nextRow0);
  }
}

// ---------------------------------------------------------------- standalone panel kernels (edges / Plan C)
__global__ __launch_bounds__(512) void pre_kernel(
    const float* __restrict__ x, const float* __restrict__ lng, const float* __restrict__ lnb,
    const __bf16* __restrict__ wihb, const float* __restrict__ bih, const float* __restrict__ bhh,
    __bf16* __restrict__ preOut, int chunkRow0){
  __shared__ SharedU sh;
  pre_panel(sh, blockIdx.x, x, lng, lnb, wihb, bih, bhh, preOut, chunkRow0);
}

__global__ __launch_bounds__(512) void ffn_kernel(
    const __bf16* __restrict__ ymidb,
    const __bf16* __restrict__ m0bf, const float* __restrict__ m0b,
    const __bf16* __restrict__ m1bf, const float* __restrict__ m1b,
    __bf16* __restrict__ a1, float* __restrict__ y2,
    const __bf16* __restrict__ awT0, const __bf16* __restrict__ awT1,
    const float* __restrict__ ab0, const float* __restrict__ ab1){
  __shared__ SharedU sh;
  ffn_panel(sh, blockIdx.x, ymidb, m0bf, m0b, m1bf, m1b, a1, y2, awT0, awT1, ab0, ab1);
}

// ---------------------------------------------------------------- launch
extern "C" void kernel_launch(void* const* d_in, const int* in_sizes, int n_in,
                              void* d_out, int out_size, void* d_ws, size_t ws_size,
                              hipStream_t stream){
  (void)in_sizes; (void)n_in; (void)out_size;
  const float* x    = (const float*)d_in[0];
  const void*  first=               d_in[1];
  const float* h0   = (const float*)d_in[2];
  const float* c0   = (const float*)d_in[3];
  const float* ln_g = (const float*)d_in[4];
  const float* ln_b = (const float*)d_in[5];
  const float* Wih  = (const float*)d_in[6];
  const float* Whh  = (const float*)d_in[7];
  const float* bih  = (const float*)d_in[8];
  const float* bhh  = (const float*)d_in[9];
  const float* m0w  = (const float*)d_in[10];
  const float* m0b  = (const float*)d_in[11];
  const float* m1w  = (const float*)d_in[12];
  const float* m1b  = (const float*)d_in[13];
  const float* aw0  = (const float*)d_in[14];
  const float* ab0  = (const float*)d_in[15];
  const float* aw1  = (const float*)d_in[16];
  const float* ab1  = (const float*)d_in[17];

  float* out  = (float*)d_out;
  float* hout = out + (size_t)TB_ * D_;
  float* cout = hout + B_ * D_;
  char* ws = (char*)d_ws;

  const bool planA = (ws_size >= (size_t)126160000ULL);

  if (planA) {
    // Plan A: overlap layout (~126.2 MB)
    __bf16* preA  = (__bf16*)(ws + 0LL);
    __bf16* preB  = (__bf16*)(ws + 33554432LL);
    __bf16* a1b   = (__bf16*)(ws + 67108864LL);
    __bf16* ymA   = (__bf16*)(ws + 100663296LL);
    __bf16* ymB   = (__bf16*)(ws + 109051904LL);
    __bf16* wihb  = (__bf16*)(ws + 117440512LL);
    __bf16* whhb  = (__bf16*)(ws + 119537664LL);
    __bf16* m0bf  = (__bf16*)(ws + 121634816LL);
    __bf16* m1bf  = (__bf16*)(ws + 123731968LL);
    __bf16* awT0  = (__bf16*)(ws + 125829120LL);
    __bf16* awT1  = (__bf16*)(ws + 125894656LL);
    unsigned long long* HP = (unsigned long long*)(ws + 125960192LL);
    float*  cstate= (float*) (ws + 126091264LL);
    unsigned int* mode = (unsigned int*)(ws + 126156800LL);

    hipMemsetAsync(HP, 0, 131072, stream);
    detect_first_kernel<<<1, 256, 0, stream>>>((const unsigned char*)first, mode);
    convert_w_kernel<<<4352, 256, 0, stream>>>(Wih, Whh, m0w, m1w, aw0, aw1,
                                               wihb, whhb, m0bf, m1bf, awT0, awT1);
    pre_kernel<<<64, 512, 0, stream>>>(x, ln_g, ln_b, wihb, bih, bhh, preA, 0);
    for (int c = 0; c < 4; ++c) {
      __bf16* preCur  = (c & 1) ? preB : preA;
      __bf16* preNext = (c & 1) ? preA : preB;
      __bf16* ymCur   = (c & 1) ? ymB : ymA;
      __bf16* ymPrev  = (c & 1) ? ymA : ymB;
      int doFfn = (c > 0), doPre = (c < 3);
      fused_scan<<<144, 512, 0, stream>>>(
          whhb, preCur, x, first, h0, c0, cstate, ymCur, HP, mode, hout, cout, c * TCH_,
          doFfn, ymPrev, m0bf, m0b, m1bf, m1b, a1b, out + (size_t)(c-1) * RCH_ * D_,
          awT0, awT1, ab0, ab1,
          doPre, ln_g, ln_b, wihb, bih, bhh, preNext, (c+1) * RCH_);
    }
    ffn_kernel<<<64, 512, 0, stream>>>(ymB, m0bf, m0b, m1bf, m1b, a1b,
                                       out + (size_t)3 * RCH_ * D_, awT0, awT1, ab0, ab1);
  } else {
    // Plan C: serial layout (~50.7 MB); a1 aliases pre (dead after scan)
    __bf16* preS  = (__bf16*)(ws + 0LL);
    __bf16* a1b   = preS;
    __bf16* ymC   = (__bf16*)(ws + 33554432LL);
    __bf16* wihb  = (__bf16*)(ws + 41943040LL);
    __bf16* whhb  = (__bf16*)(ws + 44040192LL);
    __bf16* m0bf  = (__bf16*)(ws + 46137344LL);
    __bf16* m1bf  = (__bf16*)(ws + 48234496LL);
    __bf16* awT0  = (__bf16*)(ws + 50331648LL);
    __bf16* awT1  = (__bf16*)(ws + 50397184LL);
    unsigned long long* HP = (unsigned long long*)(ws + 50462720LL);
    float*  cstate= (float*) (ws + 50593792LL);
    unsigned int* mode = (unsigned int*)(ws + 50659328LL);

    hipMemsetAsync(HP, 0, 131072, stream);
    detect_first_kernel<<<1, 256, 0, stream>>>((const unsigned char*)first, mode);
    convert_w_kernel<<<4352, 256, 0, stream>>>(Wih, Whh, m0w, m1w, aw0, aw1,
                                               wihb, whhb, m0bf, m1bf, awT0, awT1);
    for (int c = 0; c < 4; ++c) {
      pre_kernel<<<64, 512, 0, stream>>>(x, ln_g, ln_b, wihb, bih, bhh, preS, c * RCH_);
      fused_scan<<<16, 512, 0, stream>>>(
          whhb, preS, x, first, h0, c0, cstate, ymC, HP, mode, hout, cout, c * TCH_,
          0, nullptr, nullptr, nullptr, nullptr, nullptr, nullptr, nullptr,
          nullptr, nullptr, nullptr, nullptr,
          0, nullptr, nullptr, nullptr, nullptr, nullptr, nullptr, 0);
      ffn_kernel<<<64, 512, 0, stream>>>(ymC, m0bf, m0b, m1bf, m1b, a1b,
                                         out + (size_t)c * RCH_ * D_, awT0, awT1, ab0, ab1);
    }
  }
}